// Round 3
// baseline (494.301 us; speedup 1.0000x reference)
//
#include <hip/hip_runtime.h>
#include <hip/hip_bf16.h>

typedef __bf16 bf16x8 __attribute__((ext_vector_type(8)));
typedef float  f32x4  __attribute__((ext_vector_type(4)));

#define NB   64      // batch
#define NPTS 10000   // nodes
#define KC0  128     // feature channels (GEMM K)
#define NC1  64      // kernel MLP out channels
#define NC2  256     // encoder out channels (GEMM M after operand swap)
#define GN   8       // n-values per block -> 1250 blocks

// ---------------------------------------------------------------------------
// Kernel 1: precompute, parallelized over 9 blocks.
//   block 0 : k0 = MLP(0); cst = k0 @ We[128:192,:] + be   [256] exact fp32
//   block b : WeT slice — WeT[c][k] = bf16(We[k][c]), k in [(b-1)*16,(b-1)*16+16)
// ---------------------------------------------------------------------------
__global__ __launch_bounds__(256) void pe_precompute(
    const float* __restrict__ b1, const float* __restrict__ W2,
    const float* __restrict__ b2, const float* __restrict__ W3,
    const float* __restrict__ b3, const float* __restrict__ We,
    const float* __restrict__ be,
    __hip_bfloat16* __restrict__ WeT, float* __restrict__ cst)
{
    const int t  = threadIdx.x;
    const int bb = blockIdx.x;
    if (bb == 0) {
        __shared__ float sW2[8 * 16], sW3[16 * NC1], sb1[8], sb2[16], sb3[NC1], k0[NC1];
        if (t < 128) sW2[t] = W2[t];
        for (int i = t; i < 16 * NC1; i += 256) sW3[i] = W3[i];
        if (t < 8)  sb1[t] = b1[t];
        if (t < 16) sb2[t] = b2[t];
        if (t < NC1) sb3[t] = b3[t];
        __syncthreads();
        if (t < NC1) {
            float h1[8], h2[16];
            #pragma unroll
            for (int i = 0; i < 8; ++i) h1[i] = fmaxf(sb1[i], 0.f);  // x=0 -> relu(b1)
            #pragma unroll
            for (int j = 0; j < 16; ++j) {
                float s = sb2[j];
                #pragma unroll
                for (int i = 0; i < 8; ++i) s += h1[i] * sW2[i * 16 + j];
                h2[j] = fmaxf(s, 0.f);
            }
            float s = sb3[t];
            #pragma unroll
            for (int j = 0; j < 16; ++j) s += h2[j] * sW3[j * NC1 + t];
            k0[t] = s;
        }
        __syncthreads();
        float s = be[t];
        #pragma unroll 8
        for (int j = 0; j < NC1; ++j)
            s += k0[j] * We[(size_t)(KC0 + j) * NC2 + t];
        cst[t] = s;
    } else {
        const int kbase = (bb - 1) * 16;
        #pragma unroll
        for (int kr = 0; kr < 16; ++kr) {
            const int k = kbase + kr;
            WeT[(size_t)t * KC0 + k] = __float2bfloat16(We[(size_t)k * NC2 + t]);
        }
    }
}

// ---------------------------------------------------------------------------
// Kernel 2: out[n,b,c] = feature[b,n,:] @ We[:128,c] + cst[c]
// 512 threads = 8 waves; wave w owns c in [w*32, w*32+32)  -> afrag[4][2]
// (32 VGPR) + acc[2] (8 VGPR): total ~100 VGPR -> 16 waves/CU.
// No LDS, no barriers: compiler free to pipeline across the unrolled body.
// MFMA 16x16x32 layouts (m89-verified), A = WeT (c x k), B = feature (k x b):
//   A: lane l -> A[l&15][8*(l>>4)+j]        (c = lm, k = lk*8+j)
//   B: lane l -> B[8*(l>>4)+j][l&15]        (k = lk*8+j, b = lm)
//   D: lane l, reg r -> D[(l>>4)*4+r][l&15] (c = lk*4+r, b = lm)
// Lane's 4 acc elements = 4 consecutive c -> direct f32x4 store, 64B full
// sectors, no RFO. Stores are non-temporal (write-once stream).
// ---------------------------------------------------------------------------
__global__ __launch_bounds__(512) void pe_gemm(
    const float* __restrict__ feat, const __hip_bfloat16* __restrict__ WeT,
    const float* __restrict__ cst, float* __restrict__ out)
{
    const int tid  = threadIdx.x;
    const int wave = tid >> 6;     // 0..7
    const int lane = tid & 63;
    const int lm   = lane & 15;
    const int lk   = lane >> 4;
    const int cbase = wave * 32;

    // A fragments (WeT), resident for the whole block
    bf16x8 afrag[4][2];
    #pragma unroll
    for (int nn = 0; nn < 2; ++nn) {
        const __hip_bfloat16* wp = WeT + (size_t)(cbase + nn * 16 + lm) * KC0 + lk * 8;
        #pragma unroll
        for (int kk = 0; kk < 4; ++kk)
            afrag[kk][nn] = *reinterpret_cast<const bf16x8*>(wp + kk * 32);
    }
    // constant bias: lane's 4 consecutive c per c-tile
    f32x4 cv[2];
    #pragma unroll
    for (int nn = 0; nn < 2; ++nn)
        cv[nn] = *reinterpret_cast<const f32x4*>(cst + cbase + nn * 16 + lk * 4);

    for (int g = 0; g < GN; ++g) {
        const size_t n  = (size_t)blockIdx.x * GN + g;
        const float* fn = feat + n * KC0;
        #pragma unroll
        for (int h = 0; h < 2; ++h) {
            #pragma unroll
            for (int mm = 0; mm < 2; ++mm) {
                const int brow = h * 32 + mm * 16 + lm;
                const float* ap = fn + (size_t)brow * ((size_t)NPTS * KC0) + lk * 8;

                bf16x8 bfr[4];
                #pragma unroll
                for (int kk = 0; kk < 4; ++kk) {
                    f32x4 lo = *reinterpret_cast<const f32x4*>(ap + kk * 32);
                    f32x4 hi = *reinterpret_cast<const f32x4*>(ap + kk * 32 + 4);
                    bf16x8 v;
                    #pragma unroll
                    for (int j = 0; j < 4; ++j) {
                        v[j]     = (__bf16)lo[j];
                        v[j + 4] = (__bf16)hi[j];
                    }
                    bfr[kk] = v;
                }

                f32x4 acc[2];
                #pragma unroll
                for (int nn = 0; nn < 2; ++nn) acc[nn] = cv[nn];
                #pragma unroll
                for (int kk = 0; kk < 4; ++kk)
                    #pragma unroll
                    for (int nn = 0; nn < 2; ++nn)
                        acc[nn] = __builtin_amdgcn_mfma_f32_16x16x32_bf16(
                            afrag[kk][nn], bfr[kk], acc[nn], 0, 0, 0);

                // out[n, brow, cbase + nn*16 + lk*4 .. +3]
                float* op = out + (n * NB + brow) * NC2 + cbase + lk * 4;
                #pragma unroll
                for (int nn = 0; nn < 2; ++nn)
                    __builtin_nontemporal_store(
                        acc[nn], reinterpret_cast<f32x4*>(op + nn * 16));
            }
        }
    }
}

extern "C" void kernel_launch(void* const* d_in, const int* in_sizes, int n_in,
                              void* d_out, int out_size, void* d_ws, size_t ws_size,
                              hipStream_t stream) {
    const float* feat = (const float*)d_in[0];
    // d_in[1] = coordinates: unused (MLP input is identically zero)
    // d_in[2] = W1: unused (multiplies the zero vector)
    const float* b1 = (const float*)d_in[3];
    const float* W2 = (const float*)d_in[4];
    const float* b2 = (const float*)d_in[5];
    const float* W3 = (const float*)d_in[6];
    const float* b3 = (const float*)d_in[7];
    const float* We = (const float*)d_in[8];
    const float* be = (const float*)d_in[9];

    __hip_bfloat16* WeT = (__hip_bfloat16*)d_ws;                    // 256*128*2 = 64 KiB
    float*          cst = (float*)((char*)d_ws + NC2 * KC0 * 2);    // 256 floats, 16B-aligned

    pe_precompute<<<9, 256, 0, stream>>>(b1, W2, b2, W3, b3, We, be, WeT, cst);
    pe_gemm<<<NPTS / GN, 512, 0, stream>>>(feat, WeT, cst, (float*)d_out);
}

// Round 4
// 217.003 us; speedup vs baseline: 2.2778x; 2.2778x over previous
//
#include <hip/hip_runtime.h>
#include <hip/hip_bf16.h>

typedef __bf16 bf16x8 __attribute__((ext_vector_type(8)));
typedef __bf16 bf16x4 __attribute__((ext_vector_type(4)));
typedef float  f32x4  __attribute__((ext_vector_type(4)));

#define NB   64      // batch
#define NPTS 10000   // nodes
#define KC0  128     // feature channels (GEMM K)
#define NC1  64      // kernel MLP out channels
#define NC2  256     // encoder out channels (GEMM M after operand swap)
#define GN   4       // n-values (tiles) per block -> 2500 blocks

// ---------------------------------------------------------------------------
// Kernel 1: precompute, parallelized over 9 blocks.
//   block 0 : k0 = MLP(0); cst = k0 @ We[128:192,:] + be   [256] exact fp32
//   block b : WeT slice — WeT[c][k] = bf16(We[k][c]), k in [(b-1)*16,(b-1)*16+16)
// ---------------------------------------------------------------------------
__global__ __launch_bounds__(256) void pe_precompute(
    const float* __restrict__ b1, const float* __restrict__ W2,
    const float* __restrict__ b2, const float* __restrict__ W3,
    const float* __restrict__ b3, const float* __restrict__ We,
    const float* __restrict__ be,
    __hip_bfloat16* __restrict__ WeT, float* __restrict__ cst)
{
    const int t  = threadIdx.x;
    const int bb = blockIdx.x;
    if (bb == 0) {
        __shared__ float sW2[8 * 16], sW3[16 * NC1], sb1[8], sb2[16], sb3[NC1], k0[NC1];
        if (t < 128) sW2[t] = W2[t];
        for (int i = t; i < 16 * NC1; i += 256) sW3[i] = W3[i];
        if (t < 8)  sb1[t] = b1[t];
        if (t < 16) sb2[t] = b2[t];
        if (t < NC1) sb3[t] = b3[t];
        __syncthreads();
        if (t < NC1) {
            float h1[8], h2[16];
            #pragma unroll
            for (int i = 0; i < 8; ++i) h1[i] = fmaxf(sb1[i], 0.f);  // x=0 -> relu(b1)
            #pragma unroll
            for (int j = 0; j < 16; ++j) {
                float s = sb2[j];
                #pragma unroll
                for (int i = 0; i < 8; ++i) s += h1[i] * sW2[i * 16 + j];
                h2[j] = fmaxf(s, 0.f);
            }
            float s = sb3[t];
            #pragma unroll
            for (int j = 0; j < 16; ++j) s += h2[j] * sW3[j * NC1 + t];
            k0[t] = s;
        }
        __syncthreads();
        float s = be[t];
        #pragma unroll 8
        for (int j = 0; j < NC1; ++j)
            s += k0[j] * We[(size_t)(KC0 + j) * NC2 + t];
        cst[t] = s;
    } else {
        const int kbase = (bb - 1) * 16;
        #pragma unroll
        for (int kr = 0; kr < 16; ++kr) {
            const int k = kbase + kr;
            WeT[(size_t)t * KC0 + k] = __float2bfloat16(We[(size_t)k * NC2 + t]);
        }
    }
}

// ---------------------------------------------------------------------------
// Kernel 2: out[n,b,c] = feature[b,n,:] @ We[:128,c] + cst[c]
// 512 thr / 8 waves; wave w owns c in [w*32,w*32+32). 2-phase pipeline:
//   prologue: load tile0 -> regs, cvt bf16, ds_write (swizzled)
//   loop g:   issue tile g+1 global loads (stay in flight across barrier)
//             lgkmcnt(0); raw s_barrier; compute tile g from LDS (MFMA+store)
//             cvt tile g+1; ds_write other buffer
// LDS tile: bf16 [64 rows=b][128 k], 16B-granule XOR swizzle gs = gl^(row&7)
// applied at BOTH ds_write and ds_read (rule #21) -> conflict-free b128 reads.
// Each feature byte is loaded from global exactly once per block.
// MFMA 16x16x32 (m89-verified), A = WeT (c x k), B = feature (k x b):
//   A: lane l -> A[l&15][8*(l>>4)+j]        B: lane l -> B[8*(l>>4)+j][l&15]
//   D: lane l, reg r -> D[(l>>4)*4+r][l&15] (c = lk*4+r consecutive -> f32x4 st)
// ---------------------------------------------------------------------------
__global__ __launch_bounds__(512, 4) void pe_gemm(
    const float* __restrict__ feat, const __hip_bfloat16* __restrict__ WeT,
    const float* __restrict__ cst, float* __restrict__ out)
{
    __shared__ __align__(16) __bf16 sbuf[2][64 * KC0];   // 2 x 16 KB

    const int tid  = threadIdx.x;
    const int wave = tid >> 6;       // 0..7
    const int lane = tid & 63;
    const int lm   = lane & 15;
    const int lk   = lane >> 4;
    const int cbase = wave * 32;

    // staging role: thread covers row sr (b), col-octant sq (16 floats/chunk x4)
    const int sr = tid >> 3;         // 0..63
    const int sq = tid & 7;          // 0..7
    const size_t n0 = (size_t)blockIdx.x * GN;
    const float* fstage = feat + ((size_t)sr * NPTS + n0) * KC0 + sq * 4;

    // A fragments (WeT), resident for the whole block
    bf16x8 afrag[4][2];
    #pragma unroll
    for (int nn = 0; nn < 2; ++nn) {
        const __hip_bfloat16* wp = WeT + (size_t)(cbase + nn * 16 + lm) * KC0 + lk * 8;
        #pragma unroll
        for (int kk = 0; kk < 4; ++kk)
            afrag[kk][nn] = *reinterpret_cast<const bf16x8*>(wp + kk * 32);
    }
    f32x4 cv[2];
    #pragma unroll
    for (int nn = 0; nn < 2; ++nn)
        cv[nn] = *reinterpret_cast<const f32x4*>(cst + cbase + nn * 16 + lk * 4);

    // ---- prologue: stage tile 0 into sbuf[0] ----
    f32x4 L[4];
    #pragma unroll
    for (int i = 0; i < 4; ++i)
        L[i] = *reinterpret_cast<const f32x4*>(fstage + i * 32);
    #pragma unroll
    for (int i = 0; i < 4; ++i) {
        bf16x4 h;
        #pragma unroll
        for (int j = 0; j < 4; ++j) h[j] = (__bf16)L[i][j];
        const int gs = (i * 4 + (sq >> 1)) ^ (sr & 7);
        *reinterpret_cast<bf16x4*>(&sbuf[0][sr * KC0 + gs * 8 + (sq & 1) * 4]) = h;
    }

    #pragma unroll
    for (int g = 0; g < GN; ++g) {
        const int cur = g & 1;
        // issue next tile's global loads early (T14): stay in flight across
        // the raw barrier, latency hides under this tile's compute
        if (g + 1 < GN) {
            #pragma unroll
            for (int i = 0; i < 4; ++i)
                L[i] = *reinterpret_cast<const f32x4*>(fstage + (g + 1) * KC0 + i * 32);
        }
        __builtin_amdgcn_sched_barrier(0);
        asm volatile("s_waitcnt lgkmcnt(0)" ::: "memory");  // my ds_writes done
        __builtin_amdgcn_s_barrier();                       // raw: no vmcnt drain
        __builtin_amdgcn_sched_barrier(0);

        // ---- compute tile g from sbuf[cur] ----
        const size_t n = n0 + g;
        #pragma unroll
        for (int mm = 0; mm < 4; ++mm) {
            const int row = mm * 16 + lm;
            bf16x8 bfr[4];
            #pragma unroll
            for (int kk = 0; kk < 4; ++kk) {
                const int gs = (kk * 4 + lk) ^ (lm & 7);
                bfr[kk] = *reinterpret_cast<const bf16x8*>(
                    &sbuf[cur][row * KC0 + gs * 8]);
            }
            f32x4 acc0 = cv[0], acc1 = cv[1];
            #pragma unroll
            for (int kk = 0; kk < 4; ++kk) {
                acc0 = __builtin_amdgcn_mfma_f32_16x16x32_bf16(
                    afrag[kk][0], bfr[kk], acc0, 0, 0, 0);
                acc1 = __builtin_amdgcn_mfma_f32_16x16x32_bf16(
                    afrag[kk][1], bfr[kk], acc1, 0, 0, 0);
            }
            float* op = out + ((size_t)n * NB + row) * NC2 + cbase + lk * 4;
            *reinterpret_cast<f32x4*>(op)      = acc0;
            *reinterpret_cast<f32x4*>(op + 16) = acc1;
        }

        // ---- write tile g+1 into the other buffer (no barrier needed:
        // other waves' reads of sbuf[cur^1] finished before this barrier) ----
        if (g + 1 < GN) {
            #pragma unroll
            for (int i = 0; i < 4; ++i) {
                bf16x4 h;
                #pragma unroll
                for (int j = 0; j < 4; ++j) h[j] = (__bf16)L[i][j];
                const int gs = (i * 4 + (sq >> 1)) ^ (sr & 7);
                *reinterpret_cast<bf16x4*>(
                    &sbuf[cur ^ 1][sr * KC0 + gs * 8 + (sq & 1) * 4]) = h;
            }
        }
    }
}

extern "C" void kernel_launch(void* const* d_in, const int* in_sizes, int n_in,
                              void* d_out, int out_size, void* d_ws, size_t ws_size,
                              hipStream_t stream) {
    const float* feat = (const float*)d_in[0];
    // d_in[1] = coordinates: unused (MLP input is identically zero)
    // d_in[2] = W1: unused (multiplies the zero vector)
    const float* b1 = (const float*)d_in[3];
    const float* W2 = (const float*)d_in[4];
    const float* b2 = (const float*)d_in[5];
    const float* W3 = (const float*)d_in[6];
    const float* b3 = (const float*)d_in[7];
    const float* We = (const float*)d_in[8];
    const float* be = (const float*)d_in[9];

    __hip_bfloat16* WeT = (__hip_bfloat16*)d_ws;                    // 256*128*2 = 64 KiB
    float*          cst = (float*)((char*)d_ws + NC2 * KC0 * 2);    // 256 floats, 16B-aligned

    pe_precompute<<<9, 256, 0, stream>>>(b1, W2, b2, W3, b3, We, be, WeT, cst);
    pe_gemm<<<NPTS / GN, 512, 0, stream>>>(feat, WeT, cst, (float*)d_out);
}

// Round 5
// 214.143 us; speedup vs baseline: 2.3083x; 1.0134x over previous
//
#include <hip/hip_runtime.h>
#include <hip/hip_bf16.h>

typedef __bf16 bf16x8 __attribute__((ext_vector_type(8)));
typedef float  f32x4  __attribute__((ext_vector_type(4)));

#define NB   64      // batch
#define NPTS 10000   // nodes
#define KC0  128     // feature channels (GEMM K)
#define NC1  64      // kernel MLP out channels
#define NC2  256     // encoder out channels (GEMM M after operand swap)
#define GN   2       // n-values (tiles) per block -> 5000 blocks (packing)

// ---------------------------------------------------------------------------
// Kernel 1: precompute, 9 blocks.
//   block 0 : k0 = MLP(0); cst = k0 @ We[128:192,:] + be   [256] exact fp32
//   block b : WeT[c][k] = bf16(We[k][c]) for k-slice [(b-1)*16, (b-1)*16+16),
//             staged via LDS so global writes are 16B segments.
// ---------------------------------------------------------------------------
__global__ __launch_bounds__(256) void pe_precompute(
    const float* __restrict__ b1, const float* __restrict__ W2,
    const float* __restrict__ b2, const float* __restrict__ W3,
    const float* __restrict__ b3, const float* __restrict__ We,
    const float* __restrict__ be,
    __hip_bfloat16* __restrict__ WeT, float* __restrict__ cst)
{
    const int t  = threadIdx.x;
    const int bb = blockIdx.x;
    if (bb == 0) {
        __shared__ float sW2[8 * 16], sW3[16 * NC1], sb1[8], sb2[16], sb3[NC1], k0[NC1];
        if (t < 128) sW2[t] = W2[t];
        for (int i = t; i < 16 * NC1; i += 256) sW3[i] = W3[i];
        if (t < 8)  sb1[t] = b1[t];
        if (t < 16) sb2[t] = b2[t];
        if (t < NC1) sb3[t] = b3[t];
        __syncthreads();
        if (t < NC1) {
            float h1[8], h2[16];
            #pragma unroll
            for (int i = 0; i < 8; ++i) h1[i] = fmaxf(sb1[i], 0.f);  // x=0 -> relu(b1)
            #pragma unroll
            for (int j = 0; j < 16; ++j) {
                float s = sb2[j];
                #pragma unroll
                for (int i = 0; i < 8; ++i) s += h1[i] * sW2[i * 16 + j];
                h2[j] = fmaxf(s, 0.f);
            }
            float s = sb3[t];
            #pragma unroll
            for (int j = 0; j < 16; ++j) s += h2[j] * sW3[j * NC1 + t];
            k0[t] = s;
        }
        __syncthreads();
        float s = be[t];
        #pragma unroll 8
        for (int j = 0; j < NC1; ++j)
            s += k0[j] * We[(size_t)(KC0 + j) * NC2 + t];
        cst[t] = s;
    } else {
        __shared__ float sW[16][NC2];
        const int kbase = (bb - 1) * 16;
        #pragma unroll
        for (int kk = 0; kk < 16; ++kk)
            sW[kk][t] = We[(size_t)(kbase + kk) * NC2 + t];  // coalesced reads
        __syncthreads();
        // thread t = output row c: write 16 bf16 = 2 x 16B contiguous
        bf16x8 lo, hi;
        #pragma unroll
        for (int kk = 0; kk < 8; ++kk) {
            lo[kk] = (__bf16)sW[kk][t];
            hi[kk] = (__bf16)sW[kk + 8][t];
        }
        __hip_bfloat16* wp = WeT + (size_t)t * KC0 + kbase;
        *reinterpret_cast<bf16x8*>(wp)     = lo;
        *reinterpret_cast<bf16x8*>(wp + 8) = hi;
    }
}

// ---------------------------------------------------------------------------
// Kernel 2: out[n,b,c] = feature[b,n,:] @ We[:128,c] + cst[c]
// 512 thr / 8 waves; wave w owns c in [w*32,w*32+32). 2-phase pipeline:
//   prologue: load tile0 -> regs, cvt bf16, ds_write_b128 (swizzled)
//   loop g:   issue tile g+1 global loads (stay in flight across barrier)
//             lgkmcnt(0); raw s_barrier; compute tile g from LDS (MFMA+store)
//             cvt tile g+1; ds_write other buffer
// Staging: thread -> row sr=tid>>3, octant sq=tid&7; two contiguous 8-k
// segments (granules sq and 8+sq), written as ds_write_b128 with involution
// gs = g ^ (sr&7) (both sides, rule #21). Write AND read patterns are full
// bank sweeps per quarter-wave -> conflict-free.
// MFMA 16x16x32 (m89-verified), A = WeT (c x k), B = feature (k x b):
//   A: lane l -> A[l&15][8*(l>>4)+j]        B: lane l -> B[8*(l>>4)+j][l&15]
//   D: lane l, reg r -> D[(l>>4)*4+r][l&15] (c = lk*4+r consecutive -> f32x4 st)
// ---------------------------------------------------------------------------
__global__ __launch_bounds__(512, 4) void pe_gemm(
    const float* __restrict__ feat, const __hip_bfloat16* __restrict__ WeT,
    const float* __restrict__ cst, float* __restrict__ out)
{
    __shared__ __align__(16) __bf16 sbuf[2][64 * KC0];   // 2 x 16 KB

    const int tid  = threadIdx.x;
    const int wave = tid >> 6;       // 0..7
    const int lane = tid & 63;
    const int lm   = lane & 15;
    const int lk   = lane >> 4;
    const int cbase = wave * 32;

    // staging role: row sr (b), octant sq; segments k=[sq*8,+8) and [64+sq*8,+8)
    const int sr = tid >> 3;         // 0..63
    const int sq = tid & 7;          // 0..7
    const size_t n0 = (size_t)blockIdx.x * GN;
    const float* fstage = feat + ((size_t)sr * NPTS + n0) * KC0 + sq * 8;
    const int gsA = sq ^ (sr & 7);          // swizzled granule, segment A
    const int gsB = 8 + gsA;                // segment B (bit3 set, same XOR)
    __bf16* wpA = &sbuf[0][sr * KC0 + gsA * 8];
    __bf16* wpB = &sbuf[0][sr * KC0 + gsB * 8];
    const int sstep = (64 * KC0) * ((GN & 1) ? 1 : 0); // placeholder避免警告
    (void)sstep;

    // A fragments (WeT), resident for the whole block
    bf16x8 afrag[4][2];
    #pragma unroll
    for (int nn = 0; nn < 2; ++nn) {
        const __hip_bfloat16* wp = WeT + (size_t)(cbase + nn * 16 + lm) * KC0 + lk * 8;
        #pragma unroll
        for (int kk = 0; kk < 4; ++kk)
            afrag[kk][nn] = *reinterpret_cast<const bf16x8*>(wp + kk * 32);
    }
    f32x4 cv[2];
    #pragma unroll
    for (int nn = 0; nn < 2; ++nn)
        cv[nn] = *reinterpret_cast<const f32x4*>(cst + cbase + nn * 16 + lk * 4);

    // ---- prologue: stage tile 0 into sbuf[0] ----
    f32x4 L[4];
    L[0] = *reinterpret_cast<const f32x4*>(fstage);
    L[1] = *reinterpret_cast<const f32x4*>(fstage + 4);
    L[2] = *reinterpret_cast<const f32x4*>(fstage + 64);
    L[3] = *reinterpret_cast<const f32x4*>(fstage + 68);
    {
        bf16x8 hA, hB;
        #pragma unroll
        for (int j = 0; j < 4; ++j) {
            hA[j] = (__bf16)L[0][j];  hA[j + 4] = (__bf16)L[1][j];
            hB[j] = (__bf16)L[2][j];  hB[j + 4] = (__bf16)L[3][j];
        }
        *reinterpret_cast<bf16x8*>(wpA) = hA;
        *reinterpret_cast<bf16x8*>(wpB) = hB;
    }

    #pragma unroll
    for (int g = 0; g < GN; ++g) {
        const int cur = g & 1;
        // issue next tile's global loads early (T14): stay in flight across
        // the raw barrier, latency hides under this tile's compute
        if (g + 1 < GN) {
            const float* fs = fstage + (g + 1) * KC0;
            L[0] = *reinterpret_cast<const f32x4*>(fs);
            L[1] = *reinterpret_cast<const f32x4*>(fs + 4);
            L[2] = *reinterpret_cast<const f32x4*>(fs + 64);
            L[3] = *reinterpret_cast<const f32x4*>(fs + 68);
        }
        __builtin_amdgcn_sched_barrier(0);
        asm volatile("s_waitcnt lgkmcnt(0)" ::: "memory");  // my ds_writes done
        __builtin_amdgcn_s_barrier();                       // raw: no vmcnt drain
        __builtin_amdgcn_sched_barrier(0);

        // ---- compute tile g from sbuf[cur] ----
        const size_t n = n0 + g;
        #pragma unroll
        for (int mm = 0; mm < 4; ++mm) {
            const int row = mm * 16 + lm;
            bf16x8 bfr[4];
            #pragma unroll
            for (int kk = 0; kk < 4; ++kk) {
                const int gs = (kk * 4 + lk) ^ (lm & 7);
                bfr[kk] = *reinterpret_cast<const bf16x8*>(
                    &sbuf[cur][row * KC0 + gs * 8]);
            }
            f32x4 acc0 = cv[0], acc1 = cv[1];
            #pragma unroll
            for (int kk = 0; kk < 4; ++kk) {
                acc0 = __builtin_amdgcn_mfma_f32_16x16x32_bf16(
                    afrag[kk][0], bfr[kk], acc0, 0, 0, 0);
                acc1 = __builtin_amdgcn_mfma_f32_16x16x32_bf16(
                    afrag[kk][1], bfr[kk], acc1, 0, 0, 0);
            }
            float* op = out + ((size_t)n * NB + row) * NC2 + cbase + lk * 4;
            *reinterpret_cast<f32x4*>(op)      = acc0;
            *reinterpret_cast<f32x4*>(op + 16) = acc1;
        }

        // ---- write tile g+1 into the other buffer ----
        if (g + 1 < GN) {
            bf16x8 hA, hB;
            #pragma unroll
            for (int j = 0; j < 4; ++j) {
                hA[j] = (__bf16)L[0][j];  hA[j + 4] = (__bf16)L[1][j];
                hB[j] = (__bf16)L[2][j];  hB[j + 4] = (__bf16)L[3][j];
            }
            const int nxt = (cur ^ 1) * (64 * KC0);
            *reinterpret_cast<bf16x8*>(wpA + nxt) = hA;
            *reinterpret_cast<bf16x8*>(wpB + nxt) = hB;
        }
    }
}

extern "C" void kernel_launch(void* const* d_in, const int* in_sizes, int n_in,
                              void* d_out, int out_size, void* d_ws, size_t ws_size,
                              hipStream_t stream) {
    const float* feat = (const float*)d_in[0];
    // d_in[1] = coordinates: unused (MLP input is identically zero)
    // d_in[2] = W1: unused (multiplies the zero vector)
    const float* b1 = (const float*)d_in[3];
    const float* W2 = (const float*)d_in[4];
    const float* b2 = (const float*)d_in[5];
    const float* W3 = (const float*)d_in[6];
    const float* b3 = (const float*)d_in[7];
    const float* We = (const float*)d_in[8];
    const float* be = (const float*)d_in[9];

    __hip_bfloat16* WeT = (__hip_bfloat16*)d_ws;                    // 256*128*2 = 64 KiB
    float*          cst = (float*)((char*)d_ws + NC2 * KC0 * 2);    // 256 floats, 16B-aligned

    pe_precompute<<<9, 256, 0, stream>>>(b1, W2, b2, W3, b3, We, be, WeT, cst);
    pe_gemm<<<NPTS / GN, 512, 0, stream>>>(feat, WeT, cst, (float*)d_out);
}

// Round 6
// 213.767 us; speedup vs baseline: 2.3123x; 1.0018x over previous
//
#include <hip/hip_runtime.h>
#include <hip/hip_bf16.h>

typedef __bf16 bf16x8 __attribute__((ext_vector_type(8)));
typedef float  f32x4  __attribute__((ext_vector_type(4)));

#define NB   64      // batch
#define NPTS 10000   // nodes
#define KC0  128     // feature channels (GEMM K)
#define NC1  64      // kernel MLP out channels
#define NC2  256     // encoder out channels (GEMM M after operand swap)
#define GN   4       // n-tiles per block -> 2500 blocks

// ---------------------------------------------------------------------------
// Kernel 1: precompute, 9 blocks.
//   block 0 : k0 = MLP(0); cst = k0 @ We[128:192,:] + be   [256] exact fp32
//   block b : WeT[c][k] = bf16(We[k][c]) for k-slice [(b-1)*16, (b-1)*16+16),
//             staged via LDS so global writes are 16B segments.
// ---------------------------------------------------------------------------
__global__ __launch_bounds__(256) void pe_precompute(
    const float* __restrict__ b1, const float* __restrict__ W2,
    const float* __restrict__ b2, const float* __restrict__ W3,
    const float* __restrict__ b3, const float* __restrict__ We,
    const float* __restrict__ be,
    __hip_bfloat16* __restrict__ WeT, float* __restrict__ cst)
{
    const int t  = threadIdx.x;
    const int bb = blockIdx.x;
    if (bb == 0) {
        __shared__ float sW2[8 * 16], sW3[16 * NC1], sb1[8], sb2[16], sb3[NC1], k0[NC1];
        if (t < 128) sW2[t] = W2[t];
        for (int i = t; i < 16 * NC1; i += 256) sW3[i] = W3[i];
        if (t < 8)  sb1[t] = b1[t];
        if (t < 16) sb2[t] = b2[t];
        if (t < NC1) sb3[t] = b3[t];
        __syncthreads();
        if (t < NC1) {
            float h1[8], h2[16];
            #pragma unroll
            for (int i = 0; i < 8; ++i) h1[i] = fmaxf(sb1[i], 0.f);  // x=0 -> relu(b1)
            #pragma unroll
            for (int j = 0; j < 16; ++j) {
                float s = sb2[j];
                #pragma unroll
                for (int i = 0; i < 8; ++i) s += h1[i] * sW2[i * 16 + j];
                h2[j] = fmaxf(s, 0.f);
            }
            float s = sb3[t];
            #pragma unroll
            for (int j = 0; j < 16; ++j) s += h2[j] * sW3[j * NC1 + t];
            k0[t] = s;
        }
        __syncthreads();
        float s = be[t];
        #pragma unroll 8
        for (int j = 0; j < NC1; ++j)
            s += k0[j] * We[(size_t)(KC0 + j) * NC2 + t];
        cst[t] = s;
    } else {
        __shared__ float sW[16][NC2];
        const int kbase = (bb - 1) * 16;
        #pragma unroll
        for (int kk = 0; kk < 16; ++kk)
            sW[kk][t] = We[(size_t)(kbase + kk) * NC2 + t];  // coalesced reads
        __syncthreads();
        bf16x8 lo, hi;
        #pragma unroll
        for (int kk = 0; kk < 8; ++kk) {
            lo[kk] = (__bf16)sW[kk][t];
            hi[kk] = (__bf16)sW[kk + 8][t];
        }
        __hip_bfloat16* wp = WeT + (size_t)t * KC0 + kbase;
        *reinterpret_cast<bf16x8*>(wp)     = lo;
        *reinterpret_cast<bf16x8*>(wp + 8) = hi;
    }
}

// ---------------------------------------------------------------------------
// Kernel 2: out[n,b,c] = feature[b,n,:] @ We[:128,c] + cst[c]
// 512 thr / 8 waves; wave w owns c in [w*32,w*32+32).
// Depth-3 pipeline: 3 named register sets LA/LB/LC (rule #20: static only).
//   prologue: issue loads t0,t1,t2; ds_write t0
//   g=0: issue t3->LA | SYNC | compute t0 | ds_write t1 (LB, ~2 tiles old)
//   g=1:               SYNC | compute t1 | ds_write t2 (LC, ~3 tiles old)
//   g=2:               SYNC | compute t2 | ds_write t3 (LA, ~2 tiles old)
//   g=3:               SYNC | compute t3
// Every ds_write consumes loads >= 2 compute-tiles in flight (~1000 cy >
// HBM latency); the barrier carries no vmcnt drain (raw s_barrier).
// LDS: bf16 [64 b][128 k], 16B-granule involution gs = g ^ (row&7) applied
// at write AND read (rule #21) -> conflict-free b128 both sides.
// MFMA 16x16x32 (m89-verified), A = WeT (c x k), B = feature (k x b):
//   A: lane l -> A[l&15][8*(l>>4)+j]        B: lane l -> B[8*(l>>4)+j][l&15]
//   D: lane l, reg r -> D[(l>>4)*4+r][l&15] (c = lk*4+r consecutive -> f32x4 st)
// ---------------------------------------------------------------------------
#define SYNC() do { \
    __builtin_amdgcn_sched_barrier(0); \
    asm volatile("s_waitcnt lgkmcnt(0)" ::: "memory"); \
    __builtin_amdgcn_s_barrier(); \
    __builtin_amdgcn_sched_barrier(0); \
} while (0)

__global__ __launch_bounds__(512, 4) void pe_gemm(
    const float* __restrict__ feat, const __hip_bfloat16* __restrict__ WeT,
    const float* __restrict__ cst, float* __restrict__ out)
{
    __shared__ __align__(16) __bf16 sbuf[2][64 * KC0];   // 2 x 16 KB

    const int tid  = threadIdx.x;
    const int wave = tid >> 6;       // 0..7
    const int lane = tid & 63;
    const int lm   = lane & 15;
    const int lk   = lane >> 4;
    const int cbase = wave * 32;

    // staging role: row sr (b), octant sq; k-segments [sq*8,+8) and [64+sq*8,+8)
    const int sr = tid >> 3;         // 0..63
    const int sq = tid & 7;          // 0..7
    const size_t n0 = (size_t)blockIdx.x * GN;
    const float* fstage = feat + ((size_t)sr * NPTS + n0) * KC0 + sq * 8;
    const int gsA = sq ^ (sr & 7);   // swizzled granule (segment A); B = +8
    __bf16* const wp0 = &sbuf[0][sr * KC0 + gsA * 8];   // segment A, buf 0
    const int BUFSTEP = 64 * KC0;                       // buf1 = wp0 + BUFSTEP

    // A fragments (WeT) + bias, resident for the whole block
    bf16x8 afrag[4][2];
    #pragma unroll
    for (int nn = 0; nn < 2; ++nn) {
        const __hip_bfloat16* wp = WeT + (size_t)(cbase + nn * 16 + lm) * KC0 + lk * 8;
        #pragma unroll
        for (int kk = 0; kk < 4; ++kk)
            afrag[kk][nn] = *reinterpret_cast<const bf16x8*>(wp + kk * 32);
    }
    f32x4 cv0 = *reinterpret_cast<const f32x4*>(cst + cbase + lk * 4);
    f32x4 cv1 = *reinterpret_cast<const f32x4*>(cst + cbase + 16 + lk * 4);

#define LOAD_TILE(L, t) do { \
    const float* fs_ = fstage + (t) * KC0; \
    L[0] = *reinterpret_cast<const f32x4*>(fs_); \
    L[1] = *reinterpret_cast<const f32x4*>(fs_ + 4); \
    L[2] = *reinterpret_cast<const f32x4*>(fs_ + 64); \
    L[3] = *reinterpret_cast<const f32x4*>(fs_ + 68); \
} while (0)

#define WRITE_TILE(L, buf) do { \
    bf16x8 hA_, hB_; \
    _Pragma("unroll") \
    for (int j = 0; j < 4; ++j) { \
        hA_[j] = (__bf16)L[0][j];  hA_[j + 4] = (__bf16)L[1][j]; \
        hB_[j] = (__bf16)L[2][j];  hB_[j + 4] = (__bf16)L[3][j]; \
    } \
    *reinterpret_cast<bf16x8*>(wp0 + (buf) * BUFSTEP)      = hA_; \
    *reinterpret_cast<bf16x8*>(wp0 + (buf) * BUFSTEP + 64) = hB_; \
} while (0)

#define COMPUTE_TILE(t, buf) do { \
    const __bf16* sb_ = &sbuf[buf][0]; \
    float* on_ = out + ((n0 + (t)) * NB) * NC2 + cbase + lk * 4; \
    _Pragma("unroll") \
    for (int mm = 0; mm < 4; ++mm) { \
        const int row_ = mm * 16 + lm; \
        bf16x8 bfr_[4]; \
        _Pragma("unroll") \
        for (int kk = 0; kk < 4; ++kk) { \
            const int gs_ = (kk * 4 + lk) ^ (lm & 7); \
            bfr_[kk] = *reinterpret_cast<const bf16x8*>(sb_ + row_ * KC0 + gs_ * 8); \
        } \
        f32x4 a0_ = cv0, a1_ = cv1; \
        _Pragma("unroll") \
        for (int kk = 0; kk < 4; ++kk) { \
            a0_ = __builtin_amdgcn_mfma_f32_16x16x32_bf16(afrag[kk][0], bfr_[kk], a0_, 0, 0, 0); \
            a1_ = __builtin_amdgcn_mfma_f32_16x16x32_bf16(afrag[kk][1], bfr_[kk], a1_, 0, 0, 0); \
        } \
        float* op_ = on_ + (size_t)row_ * NC2; \
        *reinterpret_cast<f32x4*>(op_)      = a0_; \
        *reinterpret_cast<f32x4*>(op_ + 16) = a1_; \
    } \
} while (0)

    f32x4 LA[4], LB[4], LC[4];
    // prologue: 12 loads in flight, then stage tile 0
    LOAD_TILE(LA, 0);
    LOAD_TILE(LB, 1);
    LOAD_TILE(LC, 2);
    WRITE_TILE(LA, 0);          // waits only LA's 4 loads (vmcnt(8))

    LOAD_TILE(LA, 3);           // reuse set A for tile 3
    SYNC();
    COMPUTE_TILE(0, 0);
    WRITE_TILE(LB, 1);          // tile 1 -> buf1 (LB ~2 tiles in flight)

    SYNC();
    COMPUTE_TILE(1, 1);
    WRITE_TILE(LC, 0);          // tile 2 -> buf0 (readers of buf0 passed barrier)

    SYNC();
    COMPUTE_TILE(2, 0);
    WRITE_TILE(LA, 1);          // tile 3 -> buf1

    SYNC();
    COMPUTE_TILE(3, 1);

#undef LOAD_TILE
#undef WRITE_TILE
#undef COMPUTE_TILE
}

extern "C" void kernel_launch(void* const* d_in, const int* in_sizes, int n_in,
                              void* d_out, int out_size, void* d_ws, size_t ws_size,
                              hipStream_t stream) {
    const float* feat = (const float*)d_in[0];
    // d_in[1] = coordinates: unused (MLP input is identically zero)
    // d_in[2] = W1: unused (multiplies the zero vector)
    const float* b1 = (const float*)d_in[3];
    const float* W2 = (const float*)d_in[4];
    const float* b2 = (const float*)d_in[5];
    const float* W3 = (const float*)d_in[6];
    const float* b3 = (const float*)d_in[7];
    const float* We = (const float*)d_in[8];
    const float* be = (const float*)d_in[9];

    __hip_bfloat16* WeT = (__hip_bfloat16*)d_ws;                    // 256*128*2 = 64 KiB
    float*          cst = (float*)((char*)d_ws + NC2 * KC0 * 2);    // 256 floats, 16B-aligned

    pe_precompute<<<9, 256, 0, stream>>>(b1, W2, b2, W3, b3, We, be, WeT, cst);
    pe_gemm<<<NPTS / GN, 512, 0, stream>>>(feat, WeT, cst, (float*)d_out);
}